// Round 4
// baseline (1760.712 us; speedup 1.0000x reference)
//
#include <hip/hip_runtime.h>
#include <math.h>

// ============================ MFMA types/helpers ============================
typedef short bf16x8 __attribute__((ext_vector_type(8)));   // 8 bf16 (4 VGPRs)
typedef float f32x4 __attribute__((ext_vector_type(4)));
typedef float f32x16 __attribute__((ext_vector_type(16)));

#define MFMA16(a, b, c) __builtin_amdgcn_mfma_f32_16x16x32_bf16((a), (b), (c), 0, 0, 0)
#define MFMA32(a, b, c) __builtin_amdgcn_mfma_f32_32x32x16_bf16((a), (b), (c), 0, 0, 0)

__device__ inline unsigned short bf16_rn(float x) {
    unsigned u = __float_as_uint(x);
    unsigned r = u + 0x7FFFu + ((u >> 16) & 1u);
    return (unsigned short)(r >> 16);
}
__device__ inline float bf16_to_f(unsigned short h) {
    return __uint_as_float(((unsigned)h) << 16);
}
__device__ inline void split2(float x, unsigned short* hp, unsigned short* lp) {
    unsigned short h = bf16_rn(x);
    *hp = h;
    *lp = bf16_rn(x - bf16_to_f(h));
}

// ============================ workspace layout (bytes) ============================
static constexpr size_t OFF_W1SH  = 0;           // [64co][32k] shorts  (k 27..31 zero)
static constexpr size_t OFF_W1SL  = 4096;
static constexpr size_t OFF_W2SH  = 8192;        // [128co][576k] shorts, k = khw*64+ci
static constexpr size_t OFF_W2SL  = 155648;
static constexpr size_t OFF_W3SH  = 303104;      // [256co][1152k] shorts, k = khw*128+ci
static constexpr size_t OFF_W3SL  = 892928;
static constexpr size_t OFF_CODH  = 1482752;     // [1024][256] shorts (rows>=Kc zero)
static constexpr size_t OFF_CODL  = 2007040;
static constexpr size_t OFF_CNORM = 2531328;     // [1024] f32 (3e38 for >=Kc)
static constexpr size_t OFF_COUNTS= 2535424;     // [1024] int
static constexpr size_t OFF_LOSS  = 2539520;     // f32
static constexpr size_t OFF_ENC   = 2539776;     // [65536] int
static constexpr size_t OFF_BIG   = 2801920;     // y2h(67108864)+y2l(67108864)
                                                 // post-conv3 reuse: LUT f32 (33554432) + h f32 (8388608)
static constexpr size_t OFF_FLATS = 137019648;   // fh(33554432)+fl(33554432)
                                                 // post-vq reuse: fc1wsh(4194304)+fc1wsl(4194304)

// ============================ prep1: weight/code splits ============================
__global__ __launch_bounds__(256) void prep1_kernel(
    const float* __restrict__ w1, const float* __restrict__ w2,
    const float* __restrict__ w3, const float* __restrict__ code0,
    const float* __restrict__ code1, const int* __restrict__ idxp,
    unsigned short* __restrict__ w1sh, unsigned short* __restrict__ w1sl,
    unsigned short* __restrict__ w2sh, unsigned short* __restrict__ w2sl,
    unsigned short* __restrict__ w3sh, unsigned short* __restrict__ w3sl,
    unsigned short* __restrict__ codh, unsigned short* __restrict__ codl,
    float* __restrict__ cnorm, int* __restrict__ counts, float* __restrict__ lsum)
{
    int i = blockIdx.x * 256 + threadIdx.x;
    const int Kc = (idxp[0] == 0) ? 512 : 1024;
    if (i < 2048) {                           // w1s [co][32], k=(kh*3+kw)*3+ci
        int co = i >> 5, k = i & 31;
        float v = 0.f;
        if (k < 27) {
            int khw = k / 3, ci = k - khw * 3;
            v = w1[(co * 3 + ci) * 9 + khw];
        }
        unsigned short h, l; split2(v, &h, &l);
        w1sh[i] = h; w1sl[i] = l; return;
    }
    i -= 2048;
    if (i < 73728) {                          // w2s [co][576], k=khw*64+ci
        int co = i / 576, k = i - co * 576;
        int khw = k >> 6, ci = k & 63;
        float v = w2[(co * 64 + ci) * 9 + khw];
        unsigned short h, l; split2(v, &h, &l);
        w2sh[i] = h; w2sl[i] = l; return;
    }
    i -= 73728;
    if (i < 294912) {                         // w3s [co][1152], k=khw*128+ci
        int co = i / 1152, k = i - co * 1152;
        int khw = k >> 7, ci = k & 127;
        float v = w3[(co * 128 + ci) * 9 + khw];
        unsigned short h, l; split2(v, &h, &l);
        w3sh[i] = h; w3sl[i] = l; return;
    }
    i -= 294912;
    if (i < 262144) {                         // codes [code][256]
        int code = i >> 8, c = i & 255;
        float v = 0.f;
        if (code < Kc) v = (code < 512) ? code0[code * 256 + c]
                                        : code1[(code - 512) * 256 + c];
        unsigned short h, l; split2(v, &h, &l);
        codh[i] = h; codl[i] = l; return;
    }
    i -= 262144;
    if (i < 1024) {                           // cnorm (exact fp32)
        float s;
        if (i < Kc) {
            const float* c = (i < 512) ? code0 + (size_t)i * 256
                                       : code1 + (size_t)(i - 512) * 256;
            s = 0.f;
            for (int k = 0; k < 256; ++k) s += c[k] * c[k];
        } else s = 3.0e38f;
        cnorm[i] = s; return;
    }
    i -= 1024;
    if (i < 1024) { counts[i] = 0; return; }
    i -= 1024;
    if (i == 0) lsum[0] = 0.f;
}

// ============================ conv12: fused conv1+conv2 (split-bf16 MFMA) ============================
__global__ __launch_bounds__(256, 2) void conv12_kernel(
    const float* __restrict__ x,
    const unsigned short* __restrict__ w1sh, const unsigned short* __restrict__ w1sl,
    const float* __restrict__ b1,
    const unsigned short* __restrict__ w2sh, const unsigned short* __restrict__ w2sl,
    const float* __restrict__ b2,
    unsigned short* __restrict__ y2h, unsigned short* __restrict__ y2l)
{
    __shared__ __align__(16) char smem[62496];
    float* xsp = (float*)smem;
    unsigned short* y1h = (unsigned short*)smem;
    unsigned short* y1l = (unsigned short*)(smem + 22032);
    unsigned short* Ah1 = (unsigned short*)(smem + 44064);
    unsigned short* Al1 = (unsigned short*)(smem + 53280);
    const int t = threadIdx.x;
    const int n = blockIdx.x >> 1, hh = blockIdx.x & 1;
    const int wv = t >> 6, lane = t & 63, lq = lane >> 4, lm = lane & 15;

    // ---- load x into padded LDS ----
    for (int i = t; i < 3468; i += 256) xsp[i] = 0.f;
    __syncthreads();
    const float* xn = x + (size_t)n * 3072;
    for (int i = t; i < 768; i += 256) {
        float4 v = ((const float4*)xn)[i];
        int ci = i >> 8, rem = i & 255, ih = rem >> 3, iw = (rem & 7) << 2;
        float* d = xsp + (size_t)(ci * 34 + ih + 1) * 34 + iw + 1;
        d[0] = v.x; d[1] = v.y; d[2] = v.z; d[3] = v.w;
    }
    __syncthreads();

    // ---- conv1 im2col ----
    for (int i = t; i < 4608; i += 256) {
        int px = i >> 5, k = i & 31;
        int l = px >> 4, ow = px & 15;
        float v = 0.f;
        if (k < 27 && !(hh == 0 && l == 0)) {
            int khw = k / 3, ci = k - khw * 3;
            int kh = khw / 3, kw = khw - kh * 3;
            int xr = 16 * hh - 2 + 2 * l + kh;
            int xc = 2 * ow + kw;
            v = xsp[(size_t)(ci * 34 + xr) * 34 + xc];
        }
        unsigned short vh, vl; split2(v, &vh, &vl);
        int q = k >> 3, j = k & 7;
        Ah1[(q * 144 + px) * 8 + j] = vh;
        Al1[(q * 144 + px) * 8 + j] = vl;
    }
    __syncthreads();

    // ---- zero y1 pads ----
    {
        unsigned* zh = (unsigned*)y1h; unsigned* zl = (unsigned*)y1l;
        for (int i = t; i < 612; i += 256) { zh[i] = 0u; zl[i] = 0u; }
        for (int i = t; i < 288; i += 256) {
            int l = 1 + i / 36, d = i - (l - 1) * 36;
            zh[l * 612 + d] = 0u; zl[l * 612 + d] = 0u;
        }
    }
    __syncthreads();

    // ---- conv1 via MFMA ----
    {
        f32x4 acc[9];
        #pragma unroll
        for (int mt = 0; mt < 9; ++mt) acc[mt] = (f32x4){0.f, 0.f, 0.f, 0.f};
        int co = wv * 16 + lm;
        bf16x8 bh = *(const bf16x8*)(w1sh + co * 32 + lq * 8);
        bf16x8 bl = *(const bf16x8*)(w1sl + co * 32 + lq * 8);
        #pragma unroll
        for (int mt = 0; mt < 9; ++mt) {
            bf16x8 ah = *(const bf16x8*)(Ah1 + (lq * 144 + mt * 16 + lm) * 8);
            bf16x8 al = *(const bf16x8*)(Al1 + (lq * 144 + mt * 16 + lm) * 8);
            acc[mt] = MFMA16(ah, bh, acc[mt]);
            acc[mt] = MFMA16(ah, bl, acc[mt]);
            acc[mt] = MFMA16(al, bh, acc[mt]);
        }
        float bias = b1[co];
        #pragma unroll
        for (int mt = 0; mt < 9; ++mt) {
            #pragma unroll
            for (int r = 0; r < 4; ++r) {
                int px = mt * 16 + lq * 4 + r;
                int l = px >> 4, ow = px & 15;
                if (hh == 0 && l == 0) continue;
                float v = fmaxf(acc[mt][r] + bias, 0.f);
                unsigned short vh, vl; split2(v, &vh, &vl);
                y1h[(l * 17 + ow + 1) * 72 + co] = vh;
                y1l[(l * 17 + ow + 1) * 72 + co] = vl;
            }
        }
    }
    __syncthreads();

    // ---- conv2 via MFMA ----
    {
        const int mt2 = wv >> 1, nh = wv & 1;
        f32x4 acc[4];
        #pragma unroll
        for (int i = 0; i < 4; ++i) acc[i] = (f32x4){0.f, 0.f, 0.f, 0.f};
        int px = mt2 * 16 + lm;
        int ohl = px >> 3, ow2 = px & 7;
        #pragma unroll
        for (int ks = 0; ks < 18; ++ks) {
            int khw = ks >> 1;
            int kh = khw / 3, kw = khw - kh * 3;
            int ci0 = (ks & 1) * 32 + lq * 8;
            int l = 2 * ohl + kh, c = 2 * ow2 + kw;
            bf16x8 ah = *(const bf16x8*)(y1h + (l * 17 + c) * 72 + ci0);
            bf16x8 al = *(const bf16x8*)(y1l + (l * 17 + c) * 72 + ci0);
            #pragma unroll
            for (int nt = 0; nt < 4; ++nt) {
                int co = nh * 64 + nt * 16 + lm;
                bf16x8 bh = *(const bf16x8*)(w2sh + co * 576 + ks * 32 + lq * 8);
                bf16x8 bl = *(const bf16x8*)(w2sl + co * 576 + ks * 32 + lq * 8);
                acc[nt] = MFMA16(ah, bh, acc[nt]);
                acc[nt] = MFMA16(ah, bl, acc[nt]);
                acc[nt] = MFMA16(al, bh, acc[nt]);
            }
        }
        #pragma unroll
        for (int nt = 0; nt < 4; ++nt) {
            int co = nh * 64 + nt * 16 + lm;
            float bias = b2[co];
            #pragma unroll
            for (int r = 0; r < 4; ++r) {
                int pxr = mt2 * 16 + lq * 4 + r;
                int ohr = pxr >> 3, owr = pxr & 7;
                float v = fmaxf(acc[nt][r] + bias, 0.f);
                unsigned short vh, vl; split2(v, &vh, &vl);
                size_t o = ((size_t)n * 64 + (hh * 4 + ohr) * 8 + owr) * 128 + co;
                y2h[o] = vh; y2l[o] = vl;
            }
        }
    }
}

// ============================ conv3: implicit GEMM + sum(f^2) for loss ============================
__global__ __launch_bounds__(256, 2) void conv3_kernel(
    const unsigned short* __restrict__ y2h, const unsigned short* __restrict__ y2l,
    const unsigned short* __restrict__ w3sh, const unsigned short* __restrict__ w3sl,
    const float* __restrict__ b3,
    unsigned short* __restrict__ fh, unsigned short* __restrict__ fl,
    float* __restrict__ lsum)
{
    __shared__ __align__(16) unsigned short Ah[4 * 128 * 8];
    __shared__ __align__(16) unsigned short Al[4 * 128 * 8];
    __shared__ float ps[4];
    const int t = threadIdx.x, b = blockIdx.x;
    const int wv = t >> 6, lane = t & 63, lq = lane >> 4, lm = lane & 15;
    const int mh = wv >> 1, nh = wv & 1;
    f32x4 acc[4][8];
    #pragma unroll
    for (int i = 0; i < 4; ++i)
        #pragma unroll
        for (int j = 0; j < 8; ++j) acc[i][j] = (f32x4){0.f, 0.f, 0.f, 0.f};
    const int gpx = t >> 1, gsel = t & 1;
    const int gimg = b * 8 + (gpx >> 4);
    const int gp = gpx & 15, goh = gp >> 2, gow = gp & 3;
    const unsigned short* gsrc = gsel ? y2l : y2h;
    unsigned short* gdst = gsel ? Al : Ah;

    for (int ks = 0; ks < 36; ++ks) {
        __syncthreads();
        {
            int khw = ks >> 2;
            int kh = khw / 3, kw = khw - kh * 3;
            int ci0 = (ks & 3) * 32;
            int ih = 2 * goh + kh - 1, iw = 2 * gow + kw - 1;
            if (ih >= 0 && ih < 8 && iw >= 0 && iw < 8) {
                const unsigned short* s = gsrc + ((size_t)gimg * 64 + ih * 8 + iw) * 128 + ci0;
                #pragma unroll
                for (int qq = 0; qq < 4; ++qq)
                    *(bf16x8*)(gdst + (qq * 128 + gpx) * 8) = *(const bf16x8*)(s + qq * 8);
            } else {
                #pragma unroll
                for (int qq = 0; qq < 4; ++qq)
                    *(bf16x8*)(gdst + (qq * 128 + gpx) * 8) = (bf16x8){0, 0, 0, 0, 0, 0, 0, 0};
            }
        }
        __syncthreads();
        bf16x8 ah[4], al[4];
        #pragma unroll
        for (int mt = 0; mt < 4; ++mt) {
            int mloc = mh * 64 + mt * 16 + lm;
            ah[mt] = *(const bf16x8*)(Ah + (lq * 128 + mloc) * 8);
            al[mt] = *(const bf16x8*)(Al + (lq * 128 + mloc) * 8);
        }
        #pragma unroll
        for (int nt = 0; nt < 8; ++nt) {
            int co = nh * 128 + nt * 16 + lm;
            bf16x8 bh = *(const bf16x8*)(w3sh + (size_t)co * 1152 + ks * 32 + lq * 8);
            bf16x8 bl = *(const bf16x8*)(w3sl + (size_t)co * 1152 + ks * 32 + lq * 8);
            #pragma unroll
            for (int mt = 0; mt < 4; ++mt) {
                acc[mt][nt] = MFMA16(ah[mt], bh, acc[mt][nt]);
                acc[mt][nt] = MFMA16(ah[mt], bl, acc[mt][nt]);
                acc[mt][nt] = MFMA16(al[mt], bh, acc[mt][nt]);
            }
        }
    }
    float fsq = 0.f;
    #pragma unroll
    for (int nt = 0; nt < 8; ++nt) {
        int co = nh * 128 + nt * 16 + lm;
        float bias = b3[co];
        #pragma unroll
        for (int mt = 0; mt < 4; ++mt) {
            #pragma unroll
            for (int r = 0; r < 4; ++r) {
                int mloc = mh * 64 + mt * 16 + lq * 4 + r;
                size_t row = (size_t)b * 128 + mloc;
                float v = fmaxf(acc[mt][nt][r] + bias, 0.f);
                fsq += v * v;
                unsigned short vh, vl; split2(v, &vh, &vl);
                fh[row * 256 + co] = vh;
                fl[row * 256 + co] = vl;
            }
        }
    }
    // block-reduce sum(f^2) -> lsum
    #pragma unroll
    for (int m = 1; m <= 32; m <<= 1) fsq += __shfl_xor(fsq, m);
    if (lane == 0) ps[wv] = fsq;
    __syncthreads();
    if (t == 0) atomicAdd(lsum, ps[0] + ps[1] + ps[2] + ps[3]);
}

// ============================ vq: register-resident rows, streamed codes ============================
// wave = 32 rows (A-frags for full K=256 in regs); block = 4 waves = 128 rows.
// No LDS, no barriers. Codes streamed from L2 as 32x32x16 B-frags, 2 tiles in flight.
__global__ __launch_bounds__(256, 2) void vq_kernel(
    const unsigned short* __restrict__ fh, const unsigned short* __restrict__ fl,
    const unsigned short* __restrict__ codh, const unsigned short* __restrict__ codl,
    const float* __restrict__ cnorm, const int* __restrict__ idxp,
    int* __restrict__ enc, int* __restrict__ counts, float* __restrict__ lsum)
{
    const int t = threadIdx.x;
    const int wv = t >> 6, lane = t & 63, l32 = lane & 31, hi = lane >> 5;
    const int r0 = blockIdx.x * 128 + wv * 32;   // 4 waves/block x 32 rows
    const int Kc = (idxp[0] == 0) ? 512 : 1024;

    // A-frags: lane holds row r0+l32, k-chunk hi*8, for 16 k-steps of 16
    bf16x8 ah[16], al[16];
    #pragma unroll
    for (int ks = 0; ks < 16; ++ks) {
        size_t base = (size_t)(r0 + l32) * 256 + ks * 16 + hi * 8;
        ah[ks] = *(const bf16x8*)(fh + base);
        al[ks] = *(const bf16x8*)(fl + base);
    }
    float bv[16]; int bi[16];
    #pragma unroll
    for (int r = 0; r < 16; ++r) { bv[r] = 3.0e38f; bi[r] = 0; }

    const int ntp_max = Kc >> 6;            // pairs of 32-code tiles
    for (int ntp = 0; ntp < ntp_max; ++ntp) {
        f32x16 acc0 = {0,0,0,0,0,0,0,0,0,0,0,0,0,0,0,0};
        f32x16 acc1 = {0,0,0,0,0,0,0,0,0,0,0,0,0,0,0,0};
        const int c0 = ntp * 64 + l32, c1 = c0 + 32;
        #pragma unroll
        for (int ks = 0; ks < 16; ++ks) {
            size_t ob = (size_t)c0 * 256 + ks * 16 + hi * 8;
            bf16x8 b0h = *(const bf16x8*)(codh + ob);
            bf16x8 b0l = *(const bf16x8*)(codl + ob);
            bf16x8 b1h = *(const bf16x8*)(codh + ob + 32 * 256);
            bf16x8 b1l = *(const bf16x8*)(codl + ob + 32 * 256);
            acc0 = MFMA32(ah[ks], b0h, acc0);
            acc1 = MFMA32(ah[ks], b1h, acc1);
            acc0 = MFMA32(ah[ks], b0l, acc0);
            acc1 = MFMA32(ah[ks], b1l, acc1);
            acc0 = MFMA32(al[ks], b0h, acc0);
            acc1 = MFMA32(al[ks], b1h, acc1);
        }
        float cn0 = cnorm[c0], cn1 = cnorm[c1];
        #pragma unroll
        for (int r = 0; r < 16; ++r) {
            float d0 = cn0 - 2.f * acc0[r];
            if (d0 < bv[r]) { bv[r] = d0; bi[r] = c0; }
            float d1 = cn1 - 2.f * acc1[r];
            if (d1 < bv[r]) { bv[r] = d1; bi[r] = c1; }
        }
    }
    // butterfly over the 32 code-lanes (bits 0..4): lexicographic (value, index)
    #pragma unroll
    for (int r = 0; r < 16; ++r) {
        float v = bv[r]; int i = bi[r];
        #pragma unroll
        for (int m = 1; m <= 16; m <<= 1) {
            float ov = __shfl_xor(v, m);
            int oi = __shfl_xor(i, m);
            if (ov < v || (ov == v && oi < i)) { v = ov; i = oi; }
        }
        bv[r] = v; bi[r] = i;
    }
    if (l32 == 0) {                          // lanes 0 and 32
        float s = 0.f;
        #pragma unroll
        for (int r = 0; r < 16; ++r) {
            int row = (r & 3) + 8 * (r >> 2) + 4 * hi;   // C/D row mapping (m74)
            enc[r0 + row] = bi[r];
            atomicAdd(&counts[bi[r]], 1);
            s += bv[r];
        }
        s += __shfl_down(s, 32);
        if (lane == 0) atomicAdd(lsum, s);
    }
}

// ============================ prep2: fc1 weight slices split ============================
__global__ __launch_bounds__(256) void prep2_kernel(
    const float* __restrict__ fc1w,
    unsigned short* __restrict__ f1h, unsigned short* __restrict__ f1l)
{
    int i = blockIdx.x * 256 + threadIdx.x;
    int pos = i >> 17, rem = i & 131071, o = rem >> 8, c = rem & 255;
    float v = fc1w[(size_t)o * 4096 + c * 16 + pos];
    unsigned short h, l; split2(v, &h, &l);
    f1h[i] = h; f1l[i] = l;
}

// ============================ lut: LUT[pos][code][out] ============================
__global__ __launch_bounds__(256, 2) void lut_kernel(
    const unsigned short* __restrict__ codh, const unsigned short* __restrict__ codl,
    const unsigned short* __restrict__ f1h, const unsigned short* __restrict__ f1l,
    float* __restrict__ lut)
{
    const int t = threadIdx.x, b = blockIdx.x;
    const int pos = b >> 5, sub = b & 31, mblk = sub >> 2, nblk = sub & 3;
    const int wv = t >> 6, lane = t & 63, lq = lane >> 4, lm = lane & 15;
    const int mh = wv >> 1, nh = wv & 1;
    f32x4 acc[4][4];
    #pragma unroll
    for (int i = 0; i < 4; ++i)
        #pragma unroll
        for (int j = 0; j < 4; ++j) acc[i][j] = (f32x4){0.f, 0.f, 0.f, 0.f};
    #pragma unroll
    for (int ks = 0; ks < 8; ++ks) {
        bf16x8 ah[4], al[4];
        #pragma unroll
        for (int mt = 0; mt < 4; ++mt) {
            int code = mblk * 128 + mh * 64 + mt * 16 + lm;
            ah[mt] = *(const bf16x8*)(codh + (size_t)code * 256 + ks * 32 + lq * 8);
            al[mt] = *(const bf16x8*)(codl + (size_t)code * 256 + ks * 32 + lq * 8);
        }
        #pragma unroll
        for (int nt = 0; nt < 4; ++nt) {
            int o = nblk * 128 + nh * 64 + nt * 16 + lm;
            bf16x8 bh = *(const bf16x8*)(f1h + ((size_t)pos * 512 + o) * 256 + ks * 32 + lq * 8);
            bf16x8 bl = *(const bf16x8*)(f1l + ((size_t)pos * 512 + o) * 256 + ks * 32 + lq * 8);
            #pragma unroll
            for (int mt = 0; mt < 4; ++mt) {
                acc[mt][nt] = MFMA16(ah[mt], bh, acc[mt][nt]);
                acc[mt][nt] = MFMA16(ah[mt], bl, acc[mt][nt]);
                acc[mt][nt] = MFMA16(al[mt], bh, acc[mt][nt]);
            }
        }
    }
    #pragma unroll
    for (int nt = 0; nt < 4; ++nt) {
        int o = nblk * 128 + nh * 64 + nt * 16 + lm;
        #pragma unroll
        for (int mt = 0; mt < 4; ++mt)
            #pragma unroll
            for (int r = 0; r < 4; ++r) {
                int code = mblk * 128 + mh * 64 + mt * 16 + lq * 4 + r;
                lut[((size_t)pos * 1024 + code) * 512 + o] = acc[mt][nt][r];
            }
    }
}

// ============================ hsum ============================
__device__ inline float gelu_tanh(float x) {
    float x3 = x * x * x;
    float u = 0.7978845608028654f * (x + 0.044715f * x3);
    return 0.5f * x * (1.0f + tanhf(u));
}

__global__ __launch_bounds__(256) void hsum_kernel(
    const int* __restrict__ enc, const float* __restrict__ lut,
    const float* __restrict__ fc1b, float* __restrict__ h)
{
    __shared__ int e[16];
    const int t = threadIdx.x, img = blockIdx.x;
    if (t < 16) e[t] = enc[img * 16 + t];
    __syncthreads();
    for (int rep = 0; rep < 2; ++rep) {
        int o = rep * 256 + t;
        float acc = fc1b[o];
        #pragma unroll
        for (int p = 0; p < 16; ++p)
            acc += lut[((size_t)p * 1024 + e[p]) * 512 + o];
        h[(size_t)img * 512 + o] = gelu_tanh(acc);
    }
}

// ============================ fc2 ============================
__global__ __launch_bounds__(256) void fc2_kernel(
    const float* __restrict__ h, const float* __restrict__ fc2w,
    const float* __restrict__ fc2b, float* __restrict__ out)
{
    __shared__ float ws2[10 * 512];
    const int t = threadIdx.x;
    for (int i = t; i < 5120; i += 256) ws2[i] = fc2w[i];
    __syncthreads();
    const int lane = t & 63, wv = t >> 6;
    const int n = blockIdx.x * 4 + wv;
    float acc[10];
    #pragma unroll
    for (int j = 0; j < 10; ++j) acc[j] = 0.f;
    #pragma unroll
    for (int i = 0; i < 8; ++i) {
        float hv = h[(size_t)n * 512 + lane + 64 * i];
        #pragma unroll
        for (int j = 0; j < 10; ++j) acc[j] += hv * ws2[j * 512 + lane + 64 * i];
    }
    #pragma unroll
    for (int j = 0; j < 10; ++j) {
        float v = acc[j];
        for (int off = 32; off; off >>= 1) v += __shfl_down(v, off);
        if (lane == 0) out[(size_t)n * 10 + j] = v + fc2b[j];
    }
}

// ============================ finalize ============================
__global__ __launch_bounds__(256) void finalize_kernel(
    const int* __restrict__ counts, const float* __restrict__ lsum,
    const int* __restrict__ idxp, float* __restrict__ out)
{
    __shared__ float red[256];
    const int t = threadIdx.x;
    const int Kc = (idxp[0] == 0) ? 512 : 1024;
    float s = 0.f;
    for (int k = t; k < Kc; k += 256) {
        float p = (float)counts[k] * (1.0f / 65536.0f);
        s += p * logf(p + 1e-10f);
    }
    red[t] = s;
    __syncthreads();
    for (int o = 128; o; o >>= 1) {
        if (t < o) red[t] += red[t + o];
        __syncthreads();
    }
    if (t == 0) {
        out[40960] = lsum[0] * (1.25f / 16777216.0f);
        out[40961] = expf(-red[0]);
    }
}

// ============================ launch ============================
extern "C" void kernel_launch(void* const* d_in, const int* in_sizes, int n_in,
                              void* d_out, int out_size, void* d_ws, size_t ws_size,
                              hipStream_t stream)
{
    const float* x     = (const float*)d_in[0];
    const float* w1    = (const float*)d_in[1];
    const float* b1    = (const float*)d_in[2];
    const float* w2    = (const float*)d_in[3];
    const float* b2    = (const float*)d_in[4];
    const float* w3    = (const float*)d_in[5];
    const float* b3    = (const float*)d_in[6];
    const float* code0 = (const float*)d_in[7];
    const float* code1 = (const float*)d_in[8];
    const float* fc1w  = (const float*)d_in[9];
    const float* fc1b  = (const float*)d_in[10];
    const float* fc2w  = (const float*)d_in[11];
    const float* fc2b  = (const float*)d_in[12];
    const int*   idxp  = (const int*)d_in[13];
    float* out = (float*)d_out;
    char* ws = (char*)d_ws;

    unsigned short* w1sh = (unsigned short*)(ws + OFF_W1SH);
    unsigned short* w1sl = (unsigned short*)(ws + OFF_W1SL);
    unsigned short* w2sh = (unsigned short*)(ws + OFF_W2SH);
    unsigned short* w2sl = (unsigned short*)(ws + OFF_W2SL);
    unsigned short* w3sh = (unsigned short*)(ws + OFF_W3SH);
    unsigned short* w3sl = (unsigned short*)(ws + OFF_W3SL);
    unsigned short* codh = (unsigned short*)(ws + OFF_CODH);
    unsigned short* codl = (unsigned short*)(ws + OFF_CODL);
    float* cnorm = (float*)(ws + OFF_CNORM);
    int*   counts= (int*)(ws + OFF_COUNTS);
    float* lsum  = (float*)(ws + OFF_LOSS);
    int*   enc   = (int*)(ws + OFF_ENC);
    unsigned short* y2h = (unsigned short*)(ws + OFF_BIG);
    unsigned short* y2l = (unsigned short*)(ws + OFF_BIG + 67108864);
    unsigned short* fh  = (unsigned short*)(ws + OFF_FLATS);
    unsigned short* fl  = (unsigned short*)(ws + OFF_FLATS + 33554432);
    float* lut = (float*)(ws + OFF_BIG);
    float* h   = (float*)(ws + OFF_BIG + 33554432);
    unsigned short* f1h = (unsigned short*)(ws + OFF_FLATS);
    unsigned short* f1l = (unsigned short*)(ws + OFF_FLATS + 4194304);

    prep1_kernel<<<2481, 256, 0, stream>>>(w1, w2, w3, code0, code1, idxp,
                                           w1sh, w1sl, w2sh, w2sl, w3sh, w3sl,
                                           codh, codl, cnorm, counts, lsum);
    conv12_kernel<<<8192, 256, 0, stream>>>(x, w1sh, w1sl, b1, w2sh, w2sl, b2, y2h, y2l);
    conv3_kernel<<<512, 256, 0, stream>>>(y2h, y2l, w3sh, w3sl, b3, fh, fl, lsum);
    vq_kernel<<<512, 256, 0, stream>>>(fh, fl, codh, codl, cnorm, idxp, enc, counts, lsum);
    prep2_kernel<<<8192, 256, 0, stream>>>(fc1w, f1h, f1l);
    lut_kernel<<<512, 256, 0, stream>>>(codh, codl, f1h, f1l, lut);
    hsum_kernel<<<4096, 256, 0, stream>>>(enc, lut, fc1b, h);
    fc2_kernel<<<1024, 256, 0, stream>>>(h, fc2w, fc2b, out);
    finalize_kernel<<<1, 256, 0, stream>>>(counts, lsum, idxp, out);
}

// Round 5
// 1689.983 us; speedup vs baseline: 1.0419x; 1.0419x over previous
//
#include <hip/hip_runtime.h>
#include <math.h>

// ============================ MFMA types/helpers ============================
typedef short bf16x8 __attribute__((ext_vector_type(8)));   // 8 bf16 (4 VGPRs)
typedef float f32x4 __attribute__((ext_vector_type(4)));
typedef float f32x16 __attribute__((ext_vector_type(16)));

#define MFMA16(a, b, c) __builtin_amdgcn_mfma_f32_16x16x32_bf16((a), (b), (c), 0, 0, 0)
#define MFMA32(a, b, c) __builtin_amdgcn_mfma_f32_32x32x16_bf16((a), (b), (c), 0, 0, 0)

__device__ inline unsigned short bf16_rn(float x) {
    unsigned u = __float_as_uint(x);
    unsigned r = u + 0x7FFFu + ((u >> 16) & 1u);
    return (unsigned short)(r >> 16);
}
__device__ inline float bf16_to_f(unsigned short h) {
    return __uint_as_float(((unsigned)h) << 16);
}
__device__ inline void split2(float x, unsigned short* hp, unsigned short* lp) {
    unsigned short h = bf16_rn(x);
    *hp = h;
    *lp = bf16_rn(x - bf16_to_f(h));
}

// ============================ workspace layout (bytes) ============================
static constexpr size_t OFF_W1SH  = 0;           // [64co][32k] shorts  (k 27..31 zero)
static constexpr size_t OFF_W1SL  = 4096;
static constexpr size_t OFF_W2SH  = 8192;        // [128co][576k] shorts, k = khw*64+ci
static constexpr size_t OFF_W2SL  = 155648;
static constexpr size_t OFF_W3SH  = 303104;      // [256co][1152k] shorts, k = khw*128+ci
static constexpr size_t OFF_W3SL  = 892928;
static constexpr size_t OFF_CODH  = 1482752;     // [1024][256] shorts (rows>=Kc zero)
static constexpr size_t OFF_CODL  = 2007040;
static constexpr size_t OFF_CNORM = 2531328;     // [1024] f32 (3e38 for >=Kc)
static constexpr size_t OFF_COUNTS= 2535424;     // [1024] int
static constexpr size_t OFF_LOSS  = 2539520;     // f32
static constexpr size_t OFF_ENC   = 2539776;     // [65536] int
static constexpr size_t OFF_BIG   = 2801920;     // y2h(67108864)+y2l(67108864)
                                                 // post-conv3 reuse: LUT f32 (33554432) + h f32 (8388608)
static constexpr size_t OFF_FLATS = 137019648;   // fh(33554432)+fl(33554432)
                                                 // post-vq reuse: fc1wsh(4194304)+fc1wsl(4194304)
static constexpr size_t OFF_CODS  = 204128512;   // 524288 shorts (1 MB), B-frag-swizzled codes
// total: 205177088 (< 212515840 proven in round 1)

// ============================ prep1: weight/code splits ============================
__global__ __launch_bounds__(256) void prep1_kernel(
    const float* __restrict__ w1, const float* __restrict__ w2,
    const float* __restrict__ w3, const float* __restrict__ code0,
    const float* __restrict__ code1, const int* __restrict__ idxp,
    unsigned short* __restrict__ w1sh, unsigned short* __restrict__ w1sl,
    unsigned short* __restrict__ w2sh, unsigned short* __restrict__ w2sl,
    unsigned short* __restrict__ w3sh, unsigned short* __restrict__ w3sl,
    unsigned short* __restrict__ codh, unsigned short* __restrict__ codl,
    unsigned short* __restrict__ codS,
    float* __restrict__ cnorm, int* __restrict__ counts, float* __restrict__ lsum)
{
    int i = blockIdx.x * 256 + threadIdx.x;
    const int Kc = (idxp[0] == 0) ? 512 : 1024;
    if (i < 2048) {                           // w1s [co][32], k=(kh*3+kw)*3+ci
        int co = i >> 5, k = i & 31;
        float v = 0.f;
        if (k < 27) {
            int khw = k / 3, ci = k - khw * 3;
            v = w1[(co * 3 + ci) * 9 + khw];
        }
        unsigned short h, l; split2(v, &h, &l);
        w1sh[i] = h; w1sl[i] = l; return;
    }
    i -= 2048;
    if (i < 73728) {                          // w2s [co][576], k=khw*64+ci
        int co = i / 576, k = i - co * 576;
        int khw = k >> 6, ci = k & 63;
        float v = w2[(co * 64 + ci) * 9 + khw];
        unsigned short h, l; split2(v, &h, &l);
        w2sh[i] = h; w2sl[i] = l; return;
    }
    i -= 73728;
    if (i < 294912) {                         // w3s [co][1152], k=khw*128+ci
        int co = i / 1152, k = i - co * 1152;
        int khw = k >> 7, ci = k & 127;
        float v = w3[(co * 128 + ci) * 9 + khw];
        unsigned short h, l; split2(v, &h, &l);
        w3sh[i] = h; w3sl[i] = l; return;
    }
    i -= 294912;
    if (i < 262144) {                         // codes [code][256]
        int code = i >> 8, c = i & 255;
        float v = 0.f;
        if (code < Kc) v = (code < 512) ? code0[code * 256 + c]
                                        : code1[(code - 512) * 256 + c];
        unsigned short h, l; split2(v, &h, &l);
        codh[i] = h; codl[i] = l; return;
    }
    i -= 262144;
    if (i < 1024) {                           // cnorm (exact fp32)
        float s;
        if (i < Kc) {
            const float* c = (i < 512) ? code0 + (size_t)i * 256
                                       : code1 + (size_t)(i - 512) * 256;
            s = 0.f;
            for (int k = 0; k < 256; ++k) s += c[k] * c[k];
        } else s = 3.0e38f;
        cnorm[i] = s; return;
    }
    i -= 1024;
    if (i < 1024) { counts[i] = 0; return; }
    i -= 1024;
    if (i < 524288) {                         // codS[outer][ks][tile][hl][lane][8]
        int j = i & 7, lane2 = (i >> 3) & 63, hl = (i >> 9) & 1;
        int tile = (i >> 10) & 3, ks = (i >> 12) & 15, outer = i >> 16;
        int c = outer * 128 + tile * 32 + (lane2 & 31);
        int k = ks * 16 + (lane2 >> 5) * 8 + j;
        float v = 0.f;
        if (c < Kc) v = (c < 512) ? code0[(size_t)c * 256 + k]
                                  : code1[(size_t)(c - 512) * 256 + k];
        unsigned short h, l; split2(v, &h, &l);
        codS[i] = hl ? l : h;
        return;
    }
    i -= 524288;
    if (i == 0) lsum[0] = 0.f;
}

// ============================ conv12: fused conv1+conv2 (split-bf16 MFMA) ============================
__global__ __launch_bounds__(256, 2) void conv12_kernel(
    const float* __restrict__ x,
    const unsigned short* __restrict__ w1sh, const unsigned short* __restrict__ w1sl,
    const float* __restrict__ b1,
    const unsigned short* __restrict__ w2sh, const unsigned short* __restrict__ w2sl,
    const float* __restrict__ b2,
    unsigned short* __restrict__ y2h, unsigned short* __restrict__ y2l)
{
    __shared__ __align__(16) char smem[62496];
    float* xsp = (float*)smem;
    unsigned short* y1h = (unsigned short*)smem;
    unsigned short* y1l = (unsigned short*)(smem + 22032);
    unsigned short* Ah1 = (unsigned short*)(smem + 44064);
    unsigned short* Al1 = (unsigned short*)(smem + 53280);
    const int t = threadIdx.x;
    const int n = blockIdx.x >> 1, hh = blockIdx.x & 1;
    const int wv = t >> 6, lane = t & 63, lq = lane >> 4, lm = lane & 15;

    // ---- load x into padded LDS ----
    for (int i = t; i < 3468; i += 256) xsp[i] = 0.f;
    __syncthreads();
    const float* xn = x + (size_t)n * 3072;
    for (int i = t; i < 768; i += 256) {
        float4 v = ((const float4*)xn)[i];
        int ci = i >> 8, rem = i & 255, ih = rem >> 3, iw = (rem & 7) << 2;
        float* d = xsp + (size_t)(ci * 34 + ih + 1) * 34 + iw + 1;
        d[0] = v.x; d[1] = v.y; d[2] = v.z; d[3] = v.w;
    }
    __syncthreads();

    // ---- conv1 im2col ----
    for (int i = t; i < 4608; i += 256) {
        int px = i >> 5, k = i & 31;
        int l = px >> 4, ow = px & 15;
        float v = 0.f;
        if (k < 27 && !(hh == 0 && l == 0)) {
            int khw = k / 3, ci = k - khw * 3;
            int kh = khw / 3, kw = khw - kh * 3;
            int xr = 16 * hh - 2 + 2 * l + kh;
            int xc = 2 * ow + kw;
            v = xsp[(size_t)(ci * 34 + xr) * 34 + xc];
        }
        unsigned short vh, vl; split2(v, &vh, &vl);
        int q = k >> 3, j = k & 7;
        Ah1[(q * 144 + px) * 8 + j] = vh;
        Al1[(q * 144 + px) * 8 + j] = vl;
    }
    __syncthreads();

    // ---- zero y1 pads ----
    {
        unsigned* zh = (unsigned*)y1h; unsigned* zl = (unsigned*)y1l;
        for (int i = t; i < 612; i += 256) { zh[i] = 0u; zl[i] = 0u; }
        for (int i = t; i < 288; i += 256) {
            int l = 1 + i / 36, d = i - (l - 1) * 36;
            zh[l * 612 + d] = 0u; zl[l * 612 + d] = 0u;
        }
    }
    __syncthreads();

    // ---- conv1 via MFMA ----
    {
        f32x4 acc[9];
        #pragma unroll
        for (int mt = 0; mt < 9; ++mt) acc[mt] = (f32x4){0.f, 0.f, 0.f, 0.f};
        int co = wv * 16 + lm;
        bf16x8 bh = *(const bf16x8*)(w1sh + co * 32 + lq * 8);
        bf16x8 bl = *(const bf16x8*)(w1sl + co * 32 + lq * 8);
        #pragma unroll
        for (int mt = 0; mt < 9; ++mt) {
            bf16x8 ah = *(const bf16x8*)(Ah1 + (lq * 144 + mt * 16 + lm) * 8);
            bf16x8 al = *(const bf16x8*)(Al1 + (lq * 144 + mt * 16 + lm) * 8);
            acc[mt] = MFMA16(ah, bh, acc[mt]);
            acc[mt] = MFMA16(ah, bl, acc[mt]);
            acc[mt] = MFMA16(al, bh, acc[mt]);
        }
        float bias = b1[co];
        #pragma unroll
        for (int mt = 0; mt < 9; ++mt) {
            #pragma unroll
            for (int r = 0; r < 4; ++r) {
                int px = mt * 16 + lq * 4 + r;
                int l = px >> 4, ow = px & 15;
                if (hh == 0 && l == 0) continue;
                float v = fmaxf(acc[mt][r] + bias, 0.f);
                unsigned short vh, vl; split2(v, &vh, &vl);
                y1h[(l * 17 + ow + 1) * 72 + co] = vh;
                y1l[(l * 17 + ow + 1) * 72 + co] = vl;
            }
        }
    }
    __syncthreads();

    // ---- conv2 via MFMA ----
    {
        const int mt2 = wv >> 1, nh = wv & 1;
        f32x4 acc[4];
        #pragma unroll
        for (int i = 0; i < 4; ++i) acc[i] = (f32x4){0.f, 0.f, 0.f, 0.f};
        int px = mt2 * 16 + lm;
        int ohl = px >> 3, ow2 = px & 7;
        #pragma unroll
        for (int ks = 0; ks < 18; ++ks) {
            int khw = ks >> 1;
            int kh = khw / 3, kw = khw - kh * 3;
            int ci0 = (ks & 1) * 32 + lq * 8;
            int l = 2 * ohl + kh, c = 2 * ow2 + kw;
            bf16x8 ah = *(const bf16x8*)(y1h + (l * 17 + c) * 72 + ci0);
            bf16x8 al = *(const bf16x8*)(y1l + (l * 17 + c) * 72 + ci0);
            #pragma unroll
            for (int nt = 0; nt < 4; ++nt) {
                int co = nh * 64 + nt * 16 + lm;
                bf16x8 bh = *(const bf16x8*)(w2sh + co * 576 + ks * 32 + lq * 8);
                bf16x8 bl = *(const bf16x8*)(w2sl + co * 576 + ks * 32 + lq * 8);
                acc[nt] = MFMA16(ah, bh, acc[nt]);
                acc[nt] = MFMA16(ah, bl, acc[nt]);
                acc[nt] = MFMA16(al, bh, acc[nt]);
            }
        }
        #pragma unroll
        for (int nt = 0; nt < 4; ++nt) {
            int co = nh * 64 + nt * 16 + lm;
            float bias = b2[co];
            #pragma unroll
            for (int r = 0; r < 4; ++r) {
                int pxr = mt2 * 16 + lq * 4 + r;
                int ohr = pxr >> 3, owr = pxr & 7;
                float v = fmaxf(acc[nt][r] + bias, 0.f);
                unsigned short vh, vl; split2(v, &vh, &vl);
                size_t o = ((size_t)n * 64 + (hh * 4 + ohr) * 8 + owr) * 128 + co;
                y2h[o] = vh; y2l[o] = vl;
            }
        }
    }
}

// ============================ conv3: implicit GEMM + sum(f^2) for loss ============================
__global__ __launch_bounds__(256, 2) void conv3_kernel(
    const unsigned short* __restrict__ y2h, const unsigned short* __restrict__ y2l,
    const unsigned short* __restrict__ w3sh, const unsigned short* __restrict__ w3sl,
    const float* __restrict__ b3,
    unsigned short* __restrict__ fh, unsigned short* __restrict__ fl,
    float* __restrict__ lsum)
{
    __shared__ __align__(16) unsigned short Ah[4 * 128 * 8];
    __shared__ __align__(16) unsigned short Al[4 * 128 * 8];
    __shared__ float ps[4];
    const int t = threadIdx.x, b = blockIdx.x;
    const int wv = t >> 6, lane = t & 63, lq = lane >> 4, lm = lane & 15;
    const int mh = wv >> 1, nh = wv & 1;
    f32x4 acc[4][8];
    #pragma unroll
    for (int i = 0; i < 4; ++i)
        #pragma unroll
        for (int j = 0; j < 8; ++j) acc[i][j] = (f32x4){0.f, 0.f, 0.f, 0.f};
    const int gpx = t >> 1, gsel = t & 1;
    const int gimg = b * 8 + (gpx >> 4);
    const int gp = gpx & 15, goh = gp >> 2, gow = gp & 3;
    const unsigned short* gsrc = gsel ? y2l : y2h;
    unsigned short* gdst = gsel ? Al : Ah;

    for (int ks = 0; ks < 36; ++ks) {
        __syncthreads();
        {
            int khw = ks >> 2;
            int kh = khw / 3, kw = khw - kh * 3;
            int ci0 = (ks & 3) * 32;
            int ih = 2 * goh + kh - 1, iw = 2 * gow + kw - 1;
            if (ih >= 0 && ih < 8 && iw >= 0 && iw < 8) {
                const unsigned short* s = gsrc + ((size_t)gimg * 64 + ih * 8 + iw) * 128 + ci0;
                #pragma unroll
                for (int qq = 0; qq < 4; ++qq)
                    *(bf16x8*)(gdst + (qq * 128 + gpx) * 8) = *(const bf16x8*)(s + qq * 8);
            } else {
                #pragma unroll
                for (int qq = 0; qq < 4; ++qq)
                    *(bf16x8*)(gdst + (qq * 128 + gpx) * 8) = (bf16x8){0, 0, 0, 0, 0, 0, 0, 0};
            }
        }
        __syncthreads();
        bf16x8 ah[4], al[4];
        #pragma unroll
        for (int mt = 0; mt < 4; ++mt) {
            int mloc = mh * 64 + mt * 16 + lm;
            ah[mt] = *(const bf16x8*)(Ah + (lq * 128 + mloc) * 8);
            al[mt] = *(const bf16x8*)(Al + (lq * 128 + mloc) * 8);
        }
        #pragma unroll
        for (int nt = 0; nt < 8; ++nt) {
            int co = nh * 128 + nt * 16 + lm;
            bf16x8 bh = *(const bf16x8*)(w3sh + (size_t)co * 1152 + ks * 32 + lq * 8);
            bf16x8 bl = *(const bf16x8*)(w3sl + (size_t)co * 1152 + ks * 32 + lq * 8);
            #pragma unroll
            for (int mt = 0; mt < 4; ++mt) {
                acc[mt][nt] = MFMA16(ah[mt], bh, acc[mt][nt]);
                acc[mt][nt] = MFMA16(ah[mt], bl, acc[mt][nt]);
                acc[mt][nt] = MFMA16(al[mt], bh, acc[mt][nt]);
            }
        }
    }
    float fsq = 0.f;
    #pragma unroll
    for (int nt = 0; nt < 8; ++nt) {
        int co = nh * 128 + nt * 16 + lm;
        float bias = b3[co];
        #pragma unroll
        for (int mt = 0; mt < 4; ++mt) {
            #pragma unroll
            for (int r = 0; r < 4; ++r) {
                int mloc = mh * 64 + mt * 16 + lq * 4 + r;
                size_t row = (size_t)b * 128 + mloc;
                float v = fmaxf(acc[mt][nt][r] + bias, 0.f);
                fsq += v * v;
                unsigned short vh, vl; split2(v, &vh, &vl);
                fh[row * 256 + co] = vh;
                fl[row * 256 + co] = vl;
            }
        }
    }
    // block-reduce sum(f^2) -> lsum
    #pragma unroll
    for (int m = 1; m <= 32; m <<= 1) fsq += __shfl_xor(fsq, m);
    if (lane == 0) ps[wv] = fsq;
    __syncthreads();
    if (t == 0) atomicAdd(lsum, ps[0] + ps[1] + ps[2] + ps[3]);
}

// ============================ vq: register rows, pre-swizzled coalesced code stream ============================
// wave = 32 rows (A-frags for full K=256 in regs); block = 4 waves = 128 rows.
// No LDS, no barriers. codS is laid out in exact B-frag order: every load is
// base + lane*16B (contiguous 1 KB per wave-instruction), consumed sequentially.
// 4 independent accumulator chains (128 codes per outer pass) for MFMA ILP.
__global__ __launch_bounds__(256, 2) void vq_kernel(
    const unsigned short* __restrict__ fh, const unsigned short* __restrict__ fl,
    const unsigned short* __restrict__ codS,
    const float* __restrict__ cnorm, const int* __restrict__ idxp,
    int* __restrict__ enc, int* __restrict__ counts, float* __restrict__ lsum)
{
    const int t = threadIdx.x;
    const int wv = t >> 6, lane = t & 63, l32 = lane & 31, hi = lane >> 5;
    const int r0 = blockIdx.x * 128 + wv * 32;   // 4 waves/block x 32 rows
    const int Kc = (idxp[0] == 0) ? 512 : 1024;

    // A-frags: lane holds row r0+l32, k-chunk hi*8, for 16 k-steps of 16
    bf16x8 ah[16], al[16];
    #pragma unroll
    for (int ks = 0; ks < 16; ++ks) {
        size_t base = (size_t)(r0 + l32) * 256 + ks * 16 + hi * 8;
        ah[ks] = *(const bf16x8*)(fh + base);
        al[ks] = *(const bf16x8*)(fl + base);
    }
    float bv[16]; int bi[16];
    #pragma unroll
    for (int r = 0; r < 16; ++r) { bv[r] = 3.0e38f; bi[r] = 0; }

    const int nouter = Kc >> 7;                  // 128 codes per outer pass
    for (int outer = 0; outer < nouter; ++outer) {
        f32x16 acc[4];
        #pragma unroll
        for (int t4 = 0; t4 < 4; ++t4)
            acc[t4] = (f32x16){0,0,0,0,0,0,0,0,0,0,0,0,0,0,0,0};
        #pragma unroll
        for (int ks = 0; ks < 16; ++ks) {
            const unsigned short* pb = codS + ((size_t)(outer * 16 + ks)) * 4096 + lane * 8;
            #pragma unroll
            for (int t4 = 0; t4 < 4; ++t4) {
                bf16x8 bh = *(const bf16x8*)(pb + (t4 * 2 + 0) * 512);
                bf16x8 bl = *(const bf16x8*)(pb + (t4 * 2 + 1) * 512);
                acc[t4] = MFMA32(ah[ks], bh, acc[t4]);
                acc[t4] = MFMA32(ah[ks], bl, acc[t4]);
                acc[t4] = MFMA32(al[ks], bh, acc[t4]);
            }
        }
        #pragma unroll
        for (int t4 = 0; t4 < 4; ++t4) {
            int code = outer * 128 + t4 * 32 + l32;
            float cn = cnorm[code];
            #pragma unroll
            for (int r = 0; r < 16; ++r) {
                float d = cn - 2.f * acc[t4][r];
                if (d < bv[r]) { bv[r] = d; bi[r] = code; }
            }
        }
    }
    // butterfly over the 32 code-lanes (bits 0..4): lexicographic (value, index)
    #pragma unroll
    for (int r = 0; r < 16; ++r) {
        float v = bv[r]; int i = bi[r];
        #pragma unroll
        for (int m = 1; m <= 16; m <<= 1) {
            float ov = __shfl_xor(v, m);
            int oi = __shfl_xor(i, m);
            if (ov < v || (ov == v && oi < i)) { v = ov; i = oi; }
        }
        bv[r] = v; bi[r] = i;
    }
    if (l32 == 0) {                          // lanes 0 and 32
        float s = 0.f;
        #pragma unroll
        for (int r = 0; r < 16; ++r) {
            int row = (r & 3) + 8 * (r >> 2) + 4 * hi;   // C/D row mapping (m74)
            enc[r0 + row] = bi[r];
            atomicAdd(&counts[bi[r]], 1);
            s += bv[r];
        }
        s += __shfl_down(s, 32);
        if (lane == 0) atomicAdd(lsum, s);
    }
}

// ============================ prep2: fc1 weight slices split ============================
__global__ __launch_bounds__(256) void prep2_kernel(
    const float* __restrict__ fc1w,
    unsigned short* __restrict__ f1h, unsigned short* __restrict__ f1l)
{
    int i = blockIdx.x * 256 + threadIdx.x;
    int pos = i >> 17, rem = i & 131071, o = rem >> 8, c = rem & 255;
    float v = fc1w[(size_t)o * 4096 + c * 16 + pos];
    unsigned short h, l; split2(v, &h, &l);
    f1h[i] = h; f1l[i] = l;
}

// ============================ lut: LUT[pos][code][out] ============================
__global__ __launch_bounds__(256, 2) void lut_kernel(
    const unsigned short* __restrict__ codh, const unsigned short* __restrict__ codl,
    const unsigned short* __restrict__ f1h, const unsigned short* __restrict__ f1l,
    float* __restrict__ lut)
{
    const int t = threadIdx.x, b = blockIdx.x;
    const int pos = b >> 5, sub = b & 31, mblk = sub >> 2, nblk = sub & 3;
    const int wv = t >> 6, lane = t & 63, lq = lane >> 4, lm = lane & 15;
    const int mh = wv >> 1, nh = wv & 1;
    f32x4 acc[4][4];
    #pragma unroll
    for (int i = 0; i < 4; ++i)
        #pragma unroll
        for (int j = 0; j < 4; ++j) acc[i][j] = (f32x4){0.f, 0.f, 0.f, 0.f};
    #pragma unroll
    for (int ks = 0; ks < 8; ++ks) {
        bf16x8 ah[4], al[4];
        #pragma unroll
        for (int mt = 0; mt < 4; ++mt) {
            int code = mblk * 128 + mh * 64 + mt * 16 + lm;
            ah[mt] = *(const bf16x8*)(codh + (size_t)code * 256 + ks * 32 + lq * 8);
            al[mt] = *(const bf16x8*)(codl + (size_t)code * 256 + ks * 32 + lq * 8);
        }
        #pragma unroll
        for (int nt = 0; nt < 4; ++nt) {
            int o = nblk * 128 + nh * 64 + nt * 16 + lm;
            bf16x8 bh = *(const bf16x8*)(f1h + ((size_t)pos * 512 + o) * 256 + ks * 32 + lq * 8);
            bf16x8 bl = *(const bf16x8*)(f1l + ((size_t)pos * 512 + o) * 256 + ks * 32 + lq * 8);
            #pragma unroll
            for (int mt = 0; mt < 4; ++mt) {
                acc[mt][nt] = MFMA16(ah[mt], bh, acc[mt][nt]);
                acc[mt][nt] = MFMA16(ah[mt], bl, acc[mt][nt]);
                acc[mt][nt] = MFMA16(al[mt], bh, acc[mt][nt]);
            }
        }
    }
    #pragma unroll
    for (int nt = 0; nt < 4; ++nt) {
        int o = nblk * 128 + nh * 64 + nt * 16 + lm;
        #pragma unroll
        for (int mt = 0; mt < 4; ++mt)
            #pragma unroll
            for (int r = 0; r < 4; ++r) {
                int code = mblk * 128 + mh * 64 + mt * 16 + lq * 4 + r;
                lut[((size_t)pos * 1024 + code) * 512 + o] = acc[mt][nt][r];
            }
    }
}

// ============================ hsum ============================
__device__ inline float gelu_tanh(float x) {
    float x3 = x * x * x;
    float u = 0.7978845608028654f * (x + 0.044715f * x3);
    return 0.5f * x * (1.0f + tanhf(u));
}

__global__ __launch_bounds__(256) void hsum_kernel(
    const int* __restrict__ enc, const float* __restrict__ lut,
    const float* __restrict__ fc1b, float* __restrict__ h)
{
    __shared__ int e[16];
    const int t = threadIdx.x, img = blockIdx.x;
    if (t < 16) e[t] = enc[img * 16 + t];
    __syncthreads();
    for (int rep = 0; rep < 2; ++rep) {
        int o = rep * 256 + t;
        float acc = fc1b[o];
        #pragma unroll
        for (int p = 0; p < 16; ++p)
            acc += lut[((size_t)p * 1024 + e[p]) * 512 + o];
        h[(size_t)img * 512 + o] = gelu_tanh(acc);
    }
}

// ============================ fc2 ============================
__global__ __launch_bounds__(256) void fc2_kernel(
    const float* __restrict__ h, const float* __restrict__ fc2w,
    const float* __restrict__ fc2b, float* __restrict__ out)
{
    __shared__ float ws2[10 * 512];
    const int t = threadIdx.x;
    for (int i = t; i < 5120; i += 256) ws2[i] = fc2w[i];
    __syncthreads();
    const int lane = t & 63, wv = t >> 6;
    const int n = blockIdx.x * 4 + wv;
    float acc[10];
    #pragma unroll
    for (int j = 0; j < 10; ++j) acc[j] = 0.f;
    #pragma unroll
    for (int i = 0; i < 8; ++i) {
        float hv = h[(size_t)n * 512 + lane + 64 * i];
        #pragma unroll
        for (int j = 0; j < 10; ++j) acc[j] += hv * ws2[j * 512 + lane + 64 * i];
    }
    #pragma unroll
    for (int j = 0; j < 10; ++j) {
        float v = acc[j];
        for (int off = 32; off; off >>= 1) v += __shfl_down(v, off);
        if (lane == 0) out[(size_t)n * 10 + j] = v + fc2b[j];
    }
}

// ============================ finalize ============================
__global__ __launch_bounds__(256) void finalize_kernel(
    const int* __restrict__ counts, const float* __restrict__ lsum,
    const int* __restrict__ idxp, float* __restrict__ out)
{
    __shared__ float red[256];
    const int t = threadIdx.x;
    const int Kc = (idxp[0] == 0) ? 512 : 1024;
    float s = 0.f;
    for (int k = t; k < Kc; k += 256) {
        float p = (float)counts[k] * (1.0f / 65536.0f);
        s += p * logf(p + 1e-10f);
    }
    red[t] = s;
    __syncthreads();
    for (int o = 128; o; o >>= 1) {
        if (t < o) red[t] += red[t + o];
        __syncthreads();
    }
    if (t == 0) {
        out[40960] = lsum[0] * (1.25f / 16777216.0f);
        out[40961] = expf(-red[0]);
    }
}

// ============================ launch ============================
extern "C" void kernel_launch(void* const* d_in, const int* in_sizes, int n_in,
                              void* d_out, int out_size, void* d_ws, size_t ws_size,
                              hipStream_t stream)
{
    const float* x     = (const float*)d_in[0];
    const float* w1    = (const float*)d_in[1];
    const float* b1    = (const float*)d_in[2];
    const float* w2    = (const float*)d_in[3];
    const float* b2    = (const float*)d_in[4];
    const float* w3    = (const float*)d_in[5];
    const float* b3    = (const float*)d_in[6];
    const float* code0 = (const float*)d_in[7];
    const float* code1 = (const float*)d_in[8];
    const float* fc1w  = (const float*)d_in[9];
    const float* fc1b  = (const float*)d_in[10];
    const float* fc2w  = (const float*)d_in[11];
    const float* fc2b  = (const float*)d_in[12];
    const int*   idxp  = (const int*)d_in[13];
    float* out = (float*)d_out;
    char* ws = (char*)d_ws;

    unsigned short* w1sh = (unsigned short*)(ws + OFF_W1SH);
    unsigned short* w1sl = (unsigned short*)(ws + OFF_W1SL);
    unsigned short* w2sh = (unsigned short*)(ws + OFF_W2SH);
    unsigned short* w2sl = (unsigned short*)(ws + OFF_W2SL);
    unsigned short* w3sh = (unsigned short*)(ws + OFF_W3SH);
    unsigned short* w3sl = (unsigned short*)(ws + OFF_W3SL);
    unsigned short* codh = (unsigned short*)(ws + OFF_CODH);
    unsigned short* codl = (unsigned short*)(ws + OFF_CODL);
    unsigned short* codSp= (unsigned short*)(ws + OFF_CODS);
    float* cnorm = (float*)(ws + OFF_CNORM);
    int*   counts= (int*)(ws + OFF_COUNTS);
    float* lsum  = (float*)(ws + OFF_LOSS);
    int*   enc   = (int*)(ws + OFF_ENC);
    unsigned short* y2h = (unsigned short*)(ws + OFF_BIG);
    unsigned short* y2l = (unsigned short*)(ws + OFF_BIG + 67108864);
    unsigned short* fh  = (unsigned short*)(ws + OFF_FLATS);
    unsigned short* fl  = (unsigned short*)(ws + OFF_FLATS + 33554432);
    float* lut = (float*)(ws + OFF_BIG);
    float* h   = (float*)(ws + OFF_BIG + 33554432);
    unsigned short* f1h = (unsigned short*)(ws + OFF_FLATS);
    unsigned short* f1l = (unsigned short*)(ws + OFF_FLATS + 4194304);

    prep1_kernel<<<4529, 256, 0, stream>>>(w1, w2, w3, code0, code1, idxp,
                                           w1sh, w1sl, w2sh, w2sl, w3sh, w3sl,
                                           codh, codl, codSp, cnorm, counts, lsum);
    conv12_kernel<<<8192, 256, 0, stream>>>(x, w1sh, w1sl, b1, w2sh, w2sl, b2, y2h, y2l);
    conv3_kernel<<<512, 256, 0, stream>>>(y2h, y2l, w3sh, w3sl, b3, fh, fl, lsum);
    vq_kernel<<<512, 256, 0, stream>>>(fh, fl, codSp, cnorm, idxp, enc, counts, lsum);
    prep2_kernel<<<8192, 256, 0, stream>>>(fc1w, f1h, f1l);
    lut_kernel<<<512, 256, 0, stream>>>(codh, codl, f1h, f1l, lut);
    hsum_kernel<<<4096, 256, 0, stream>>>(enc, lut, fc1b, h);
    fc2_kernel<<<1024, 256, 0, stream>>>(h, fc2w, fc2b, out);
    finalize_kernel<<<1, 256, 0, stream>>>(counts, lsum, idxp, out);
}

// Round 6
// 1651.902 us; speedup vs baseline: 1.0659x; 1.0231x over previous
//
#include <hip/hip_runtime.h>
#include <math.h>

// ============================ MFMA types/helpers ============================
typedef short bf16x8 __attribute__((ext_vector_type(8)));   // 8 bf16 (4 VGPRs)
typedef float f32x4 __attribute__((ext_vector_type(4)));

#define MFMA16(a, b, c) __builtin_amdgcn_mfma_f32_16x16x32_bf16((a), (b), (c), 0, 0, 0)

__device__ inline unsigned short bf16_rn(float x) {
    unsigned u = __float_as_uint(x);
    unsigned r = u + 0x7FFFu + ((u >> 16) & 1u);
    return (unsigned short)(r >> 16);
}
__device__ inline float bf16_to_f(unsigned short h) {
    return __uint_as_float(((unsigned)h) << 16);
}
__device__ inline void split2(float x, unsigned short* hp, unsigned short* lp) {
    unsigned short h = bf16_rn(x);
    *hp = h;
    *lp = bf16_rn(x - bf16_to_f(h));
}

// ============================ workspace layout (bytes) ============================
static constexpr size_t OFF_W1SH  = 0;           // [64co][32k] shorts  (k 27..31 zero)
static constexpr size_t OFF_W1SL  = 4096;
static constexpr size_t OFF_W2SH  = 8192;        // [128co][576k] shorts, k = khw*64+ci
static constexpr size_t OFF_W2SL  = 155648;
static constexpr size_t OFF_W3SH  = 303104;      // [256co][1152k] shorts, k = khw*128+ci
static constexpr size_t OFF_W3SL  = 892928;
static constexpr size_t OFF_CODH  = 1482752;     // [1024][256] shorts (rows>=Kc zero)
static constexpr size_t OFF_CODL  = 2007040;
static constexpr size_t OFF_CNORM = 2531328;     // [1024] f32 (3e38 for >=Kc)
static constexpr size_t OFF_COUNTS= 2535424;     // [1024] int
static constexpr size_t OFF_LOSS  = 2539520;     // f32
static constexpr size_t OFF_ENC   = 2539776;     // [65536] int
static constexpr size_t OFF_BIG   = 2801920;     // y2h(67108864)+y2l(67108864)
                                                 // post-conv3 reuse: LUT f32 (33554432) + h f32 (8388608)
static constexpr size_t OFF_FLATS = 137019648;   // fhS(33554432)+flS(33554432), k-chunk-major [kc32][row65536][8]
                                                 // post-vq reuse: fc1wsh(4194304)+fc1wsl(4194304)
static constexpr size_t OFF_CODS  = 204128512;   // 524288 shorts (1 MB), 16x16-B-frag-swizzled codes
// total: 205177088 (< 212515840 proven in round 1)

// ============================ prep1: weight/code splits ============================
__global__ __launch_bounds__(256) void prep1_kernel(
    const float* __restrict__ w1, const float* __restrict__ w2,
    const float* __restrict__ w3, const float* __restrict__ code0,
    const float* __restrict__ code1, const int* __restrict__ idxp,
    unsigned short* __restrict__ w1sh, unsigned short* __restrict__ w1sl,
    unsigned short* __restrict__ w2sh, unsigned short* __restrict__ w2sl,
    unsigned short* __restrict__ w3sh, unsigned short* __restrict__ w3sl,
    unsigned short* __restrict__ codh, unsigned short* __restrict__ codl,
    unsigned short* __restrict__ codT,
    float* __restrict__ cnorm, int* __restrict__ counts, float* __restrict__ lsum)
{
    int i = blockIdx.x * 256 + threadIdx.x;
    const int Kc = (idxp[0] == 0) ? 512 : 1024;
    if (i < 2048) {                           // w1s [co][32], k=(kh*3+kw)*3+ci
        int co = i >> 5, k = i & 31;
        float v = 0.f;
        if (k < 27) {
            int khw = k / 3, ci = k - khw * 3;
            v = w1[(co * 3 + ci) * 9 + khw];
        }
        unsigned short h, l; split2(v, &h, &l);
        w1sh[i] = h; w1sl[i] = l; return;
    }
    i -= 2048;
    if (i < 73728) {                          // w2s [co][576], k=khw*64+ci
        int co = i / 576, k = i - co * 576;
        int khw = k >> 6, ci = k & 63;
        float v = w2[(co * 64 + ci) * 9 + khw];
        unsigned short h, l; split2(v, &h, &l);
        w2sh[i] = h; w2sl[i] = l; return;
    }
    i -= 73728;
    if (i < 294912) {                         // w3s [co][1152], k=khw*128+ci
        int co = i / 1152, k = i - co * 1152;
        int khw = k >> 7, ci = k & 127;
        float v = w3[(co * 128 + ci) * 9 + khw];
        unsigned short h, l; split2(v, &h, &l);
        w3sh[i] = h; w3sl[i] = l; return;
    }
    i -= 294912;
    if (i < 262144) {                         // codes [code][256]
        int code = i >> 8, c = i & 255;
        float v = 0.f;
        if (code < Kc) v = (code < 512) ? code0[code * 256 + c]
                                        : code1[(code - 512) * 256 + c];
        unsigned short h, l; split2(v, &h, &l);
        codh[i] = h; codl[i] = l; return;
    }
    i -= 262144;
    if (i < 1024) {                           // cnorm (exact fp32)
        float s;
        if (i < Kc) {
            const float* c = (i < 512) ? code0 + (size_t)i * 256
                                       : code1 + (size_t)(i - 512) * 256;
            s = 0.f;
            for (int k = 0; k < 256; ++k) s += c[k] * c[k];
        } else s = 3.0e38f;
        cnorm[i] = s; return;
    }
    i -= 1024;
    if (i < 1024) { counts[i] = 0; return; }
    i -= 1024;
    if (i < 524288) {                         // codT[outer16][ks8][tile4][hl2][lane64][8]
        int j = i & 7, lane2 = (i >> 3) & 63, hl = (i >> 9) & 1;
        int tile = (i >> 10) & 3, ks = (i >> 12) & 7, outer = i >> 15;
        int c = outer * 64 + tile * 16 + (lane2 & 15);      // code at lm
        int k = ks * 32 + (lane2 >> 4) * 8 + j;             // k at lq*8+j
        float v = 0.f;
        if (c < Kc) v = (c < 512) ? code0[(size_t)c * 256 + k]
                                  : code1[(size_t)(c - 512) * 256 + k];
        unsigned short h, l; split2(v, &h, &l);
        codT[i] = hl ? l : h;
        return;
    }
    i -= 524288;
    if (i == 0) lsum[0] = 0.f;
}

// ============================ conv12: fused conv1+conv2 (split-bf16 MFMA) ============================
__global__ __launch_bounds__(256, 2) void conv12_kernel(
    const float* __restrict__ x,
    const unsigned short* __restrict__ w1sh, const unsigned short* __restrict__ w1sl,
    const float* __restrict__ b1,
    const unsigned short* __restrict__ w2sh, const unsigned short* __restrict__ w2sl,
    const float* __restrict__ b2,
    unsigned short* __restrict__ y2h, unsigned short* __restrict__ y2l)
{
    __shared__ __align__(16) char smem[62496];
    float* xsp = (float*)smem;
    unsigned short* y1h = (unsigned short*)smem;
    unsigned short* y1l = (unsigned short*)(smem + 22032);
    unsigned short* Ah1 = (unsigned short*)(smem + 44064);
    unsigned short* Al1 = (unsigned short*)(smem + 53280);
    const int t = threadIdx.x;
    const int n = blockIdx.x >> 1, hh = blockIdx.x & 1;
    const int wv = t >> 6, lane = t & 63, lq = lane >> 4, lm = lane & 15;

    // ---- load x into padded LDS ----
    for (int i = t; i < 3468; i += 256) xsp[i] = 0.f;
    __syncthreads();
    const float* xn = x + (size_t)n * 3072;
    for (int i = t; i < 768; i += 256) {
        float4 v = ((const float4*)xn)[i];
        int ci = i >> 8, rem = i & 255, ih = rem >> 3, iw = (rem & 7) << 2;
        float* d = xsp + (size_t)(ci * 34 + ih + 1) * 34 + iw + 1;
        d[0] = v.x; d[1] = v.y; d[2] = v.z; d[3] = v.w;
    }
    __syncthreads();

    // ---- conv1 im2col ----
    for (int i = t; i < 4608; i += 256) {
        int px = i >> 5, k = i & 31;
        int l = px >> 4, ow = px & 15;
        float v = 0.f;
        if (k < 27 && !(hh == 0 && l == 0)) {
            int khw = k / 3, ci = k - khw * 3;
            int kh = khw / 3, kw = khw - kh * 3;
            int xr = 16 * hh - 2 + 2 * l + kh;
            int xc = 2 * ow + kw;
            v = xsp[(size_t)(ci * 34 + xr) * 34 + xc];
        }
        unsigned short vh, vl; split2(v, &vh, &vl);
        int q = k >> 3, j = k & 7;
        Ah1[(q * 144 + px) * 8 + j] = vh;
        Al1[(q * 144 + px) * 8 + j] = vl;
    }
    __syncthreads();

    // ---- zero y1 pads ----
    {
        unsigned* zh = (unsigned*)y1h; unsigned* zl = (unsigned*)y1l;
        for (int i = t; i < 612; i += 256) { zh[i] = 0u; zl[i] = 0u; }
        for (int i = t; i < 288; i += 256) {
            int l = 1 + i / 36, d = i - (l - 1) * 36;
            zh[l * 612 + d] = 0u; zl[l * 612 + d] = 0u;
        }
    }
    __syncthreads();

    // ---- conv1 via MFMA ----
    {
        f32x4 acc[9];
        #pragma unroll
        for (int mt = 0; mt < 9; ++mt) acc[mt] = (f32x4){0.f, 0.f, 0.f, 0.f};
        int co = wv * 16 + lm;
        bf16x8 bh = *(const bf16x8*)(w1sh + co * 32 + lq * 8);
        bf16x8 bl = *(const bf16x8*)(w1sl + co * 32 + lq * 8);
        #pragma unroll
        for (int mt = 0; mt < 9; ++mt) {
            bf16x8 ah = *(const bf16x8*)(Ah1 + (lq * 144 + mt * 16 + lm) * 8);
            bf16x8 al = *(const bf16x8*)(Al1 + (lq * 144 + mt * 16 + lm) * 8);
            acc[mt] = MFMA16(ah, bh, acc[mt]);
            acc[mt] = MFMA16(ah, bl, acc[mt]);
            acc[mt] = MFMA16(al, bh, acc[mt]);
        }
        float bias = b1[co];
        #pragma unroll
        for (int mt = 0; mt < 9; ++mt) {
            #pragma unroll
            for (int r = 0; r < 4; ++r) {
                int px = mt * 16 + lq * 4 + r;
                int l = px >> 4, ow = px & 15;
                if (hh == 0 && l == 0) continue;
                float v = fmaxf(acc[mt][r] + bias, 0.f);
                unsigned short vh, vl; split2(v, &vh, &vl);
                y1h[(l * 17 + ow + 1) * 72 + co] = vh;
                y1l[(l * 17 + ow + 1) * 72 + co] = vl;
            }
        }
    }
    __syncthreads();

    // ---- conv2 via MFMA ----
    {
        const int mt2 = wv >> 1, nh = wv & 1;
        f32x4 acc[4];
        #pragma unroll
        for (int i = 0; i < 4; ++i) acc[i] = (f32x4){0.f, 0.f, 0.f, 0.f};
        int px = mt2 * 16 + lm;
        int ohl = px >> 3, ow2 = px & 7;
        #pragma unroll
        for (int ks = 0; ks < 18; ++ks) {
            int khw = ks >> 1;
            int kh = khw / 3, kw = khw - kh * 3;
            int ci0 = (ks & 1) * 32 + lq * 8;
            int l = 2 * ohl + kh, c = 2 * ow2 + kw;
            bf16x8 ah = *(const bf16x8*)(y1h + (l * 17 + c) * 72 + ci0);
            bf16x8 al = *(const bf16x8*)(y1l + (l * 17 + c) * 72 + ci0);
            #pragma unroll
            for (int nt = 0; nt < 4; ++nt) {
                int co = nh * 64 + nt * 16 + lm;
                bf16x8 bh = *(const bf16x8*)(w2sh + co * 576 + ks * 32 + lq * 8);
                bf16x8 bl = *(const bf16x8*)(w2sl + co * 576 + ks * 32 + lq * 8);
                acc[nt] = MFMA16(ah, bh, acc[nt]);
                acc[nt] = MFMA16(ah, bl, acc[nt]);
                acc[nt] = MFMA16(al, bh, acc[nt]);
            }
        }
        #pragma unroll
        for (int nt = 0; nt < 4; ++nt) {
            int co = nh * 64 + nt * 16 + lm;
            float bias = b2[co];
            #pragma unroll
            for (int r = 0; r < 4; ++r) {
                int pxr = mt2 * 16 + lq * 4 + r;
                int ohr = pxr >> 3, owr = pxr & 7;
                float v = fmaxf(acc[nt][r] + bias, 0.f);
                unsigned short vh, vl; split2(v, &vh, &vl);
                size_t o = ((size_t)n * 64 + (hh * 4 + ohr) * 8 + owr) * 128 + co;
                y2h[o] = vh; y2l[o] = vl;
            }
        }
    }
}

// ============================ conv3: implicit GEMM + sum(f^2); writes k-chunk-major flats ============================
__global__ __launch_bounds__(256, 2) void conv3_kernel(
    const unsigned short* __restrict__ y2h, const unsigned short* __restrict__ y2l,
    const unsigned short* __restrict__ w3sh, const unsigned short* __restrict__ w3sl,
    const float* __restrict__ b3,
    unsigned short* __restrict__ fhS, unsigned short* __restrict__ flS,
    float* __restrict__ lsum)
{
    __shared__ __align__(16) unsigned short Ah[4 * 128 * 8];
    __shared__ __align__(16) unsigned short Al[4 * 128 * 8];
    __shared__ float ps[4];
    const int t = threadIdx.x, b = blockIdx.x;
    const int wv = t >> 6, lane = t & 63, lq = lane >> 4, lm = lane & 15;
    const int mh = wv >> 1, nh = wv & 1;
    f32x4 acc[4][8];
    #pragma unroll
    for (int i = 0; i < 4; ++i)
        #pragma unroll
        for (int j = 0; j < 8; ++j) acc[i][j] = (f32x4){0.f, 0.f, 0.f, 0.f};
    const int gpx = t >> 1, gsel = t & 1;
    const int gimg = b * 8 + (gpx >> 4);
    const int gp = gpx & 15, goh = gp >> 2, gow = gp & 3;
    const unsigned short* gsrc = gsel ? y2l : y2h;
    unsigned short* gdst = gsel ? Al : Ah;

    for (int ks = 0; ks < 36; ++ks) {
        __syncthreads();
        {
            int khw = ks >> 2;
            int kh = khw / 3, kw = khw - kh * 3;
            int ci0 = (ks & 3) * 32;
            int ih = 2 * goh + kh - 1, iw = 2 * gow + kw - 1;
            if (ih >= 0 && ih < 8 && iw >= 0 && iw < 8) {
                const unsigned short* s = gsrc + ((size_t)gimg * 64 + ih * 8 + iw) * 128 + ci0;
                #pragma unroll
                for (int qq = 0; qq < 4; ++qq)
                    *(bf16x8*)(gdst + (qq * 128 + gpx) * 8) = *(const bf16x8*)(s + qq * 8);
            } else {
                #pragma unroll
                for (int qq = 0; qq < 4; ++qq)
                    *(bf16x8*)(gdst + (qq * 128 + gpx) * 8) = (bf16x8){0, 0, 0, 0, 0, 0, 0, 0};
            }
        }
        __syncthreads();
        bf16x8 ah[4], al[4];
        #pragma unroll
        for (int mt = 0; mt < 4; ++mt) {
            int mloc = mh * 64 + mt * 16 + lm;
            ah[mt] = *(const bf16x8*)(Ah + (lq * 128 + mloc) * 8);
            al[mt] = *(const bf16x8*)(Al + (lq * 128 + mloc) * 8);
        }
        #pragma unroll
        for (int nt = 0; nt < 8; ++nt) {
            int co = nh * 128 + nt * 16 + lm;
            bf16x8 bh = *(const bf16x8*)(w3sh + (size_t)co * 1152 + ks * 32 + lq * 8);
            bf16x8 bl = *(const bf16x8*)(w3sl + (size_t)co * 1152 + ks * 32 + lq * 8);
            #pragma unroll
            for (int mt = 0; mt < 4; ++mt) {
                acc[mt][nt] = MFMA16(ah[mt], bh, acc[mt][nt]);
                acc[mt][nt] = MFMA16(ah[mt], bl, acc[mt][nt]);
                acc[mt][nt] = MFMA16(al[mt], bh, acc[mt][nt]);
            }
        }
    }
    float fsq = 0.f;
    #pragma unroll
    for (int nt = 0; nt < 8; ++nt) {
        int co = nh * 128 + nt * 16 + lm;
        float bias = b3[co];
        int kc = co >> 3, jj = co & 7;
        #pragma unroll
        for (int mt = 0; mt < 4; ++mt) {
            #pragma unroll
            for (int r = 0; r < 4; ++r) {
                int mloc = mh * 64 + mt * 16 + lq * 4 + r;
                size_t row = (size_t)b * 128 + mloc;
                float v = fmaxf(acc[mt][nt][r] + bias, 0.f);
                fsq += v * v;
                unsigned short vh, vl; split2(v, &vh, &vl);
                size_t a = (size_t)kc * 524288 + row * 8 + jj;   // [kc][row][8]
                fhS[a] = vh;
                flS[a] = vl;
            }
        }
    }
    // block-reduce sum(f^2) -> lsum
    #pragma unroll
    for (int m = 1; m <= 32; m <<= 1) fsq += __shfl_xor(fsq, m);
    if (lane == 0) ps[wv] = fsq;
    __syncthreads();
    if (t == 0) atomicAdd(lsum, ps[0] + ps[1] + ps[2] + ps[3]);
}

// ============================ vq: 16-row waves, staggered code stream, lexicographic argmin ============================
// wave = 16 rows (A-frags 64 VGPRs); block = 4 waves = 64 rows; grid 1024.
// codT pre-swizzled to 16x16x32 B-frag order: each load = base + lane*16B (coalesced).
// Waves start the code scan at staggered offsets -> independent outstanding misses.
__global__ __launch_bounds__(256, 2) void vq_kernel(
    const unsigned short* __restrict__ fhS, const unsigned short* __restrict__ flS,
    const unsigned short* __restrict__ codT,
    const float* __restrict__ cnorm, const int* __restrict__ idxp,
    int* __restrict__ enc, int* __restrict__ counts, float* __restrict__ lsum)
{
    const int t = threadIdx.x;
    const int wv = t >> 6, lane = t & 63, lq = lane >> 4, lm = lane & 15;
    const int rb = blockIdx.x * 64 + wv * 16;    // this wave's 16 rows
    const int Kc = (idxp[0] == 0) ? 512 : 1024;
    const int nouter = Kc >> 6;                  // 64 codes per outer pass (8 or 16)
    const int omask = nouter - 1;
    const int stag = (blockIdx.x * 4 + wv) & omask;

    // A-frags: lane holds row rb+lm, k-chunk (ks*4+lq)*8, 8 elems; k-chunk-major layout
    bf16x8 ah[8], al[8];
    #pragma unroll
    for (int ks = 0; ks < 8; ++ks) {
        size_t base = ((size_t)(ks * 4 + lq) * 65536 + (size_t)(rb + lm)) * 8;
        ah[ks] = *(const bf16x8*)(fhS + base);
        al[ks] = *(const bf16x8*)(flS + base);
    }
    float bv[4]; int bi[4];
    #pragma unroll
    for (int r = 0; r < 4; ++r) { bv[r] = 3.0e38f; bi[r] = 0x7fffffff; }

    for (int o2 = 0; o2 < nouter; ++o2) {
        const int outer = (o2 + stag) & omask;
        f32x4 acc[4];
        #pragma unroll
        for (int t4 = 0; t4 < 4; ++t4) acc[t4] = (f32x4){0.f, 0.f, 0.f, 0.f};
        #pragma unroll
        for (int ks = 0; ks < 8; ++ks) {
            const unsigned short* pb = codT + ((size_t)(outer * 8 + ks)) * 4096 + lane * 8;
            #pragma unroll
            for (int t4 = 0; t4 < 4; ++t4) {
                bf16x8 bh = *(const bf16x8*)(pb + (t4 * 2 + 0) * 512);
                bf16x8 bl = *(const bf16x8*)(pb + (t4 * 2 + 1) * 512);
                acc[t4] = MFMA16(ah[ks], bh, acc[t4]);
                acc[t4] = MFMA16(ah[ks], bl, acc[t4]);
                acc[t4] = MFMA16(al[ks], bh, acc[t4]);
            }
        }
        #pragma unroll
        for (int t4 = 0; t4 < 4; ++t4) {
            int code = outer * 64 + t4 * 16 + lm;
            float cn = cnorm[code];
            #pragma unroll
            for (int r = 0; r < 4; ++r) {
                float d = cn - 2.f * acc[t4][r];
                if (d < bv[r] || (d == bv[r] && code < bi[r])) { bv[r] = d; bi[r] = code; }
            }
        }
    }
    // reduce across the 16 column-lanes (xor masks 1,2,4,8): lexicographic (value, index)
    #pragma unroll
    for (int r = 0; r < 4; ++r) {
        float v = bv[r]; int i = bi[r];
        #pragma unroll
        for (int m = 1; m <= 8; m <<= 1) {
            float ov = __shfl_xor(v, m);
            int oi = __shfl_xor(i, m);
            if (ov < v || (ov == v && oi < i)) { v = ov; i = oi; }
        }
        bv[r] = v; bi[r] = i;
    }
    float s = 0.f;
    if (lm == 0) {                               // lanes 0,16,32,48 -> rows lq*4+r
        #pragma unroll
        for (int r = 0; r < 4; ++r) {
            enc[rb + lq * 4 + r] = bi[r];
            atomicAdd(&counts[bi[r]], 1);
            s += bv[r];
        }
    }
    s += __shfl_xor(s, 16);
    s += __shfl_xor(s, 32);
    if (lane == 0) atomicAdd(lsum, s);
}

// ============================ prep2: fc1 weight slices split ============================
__global__ __launch_bounds__(256) void prep2_kernel(
    const float* __restrict__ fc1w,
    unsigned short* __restrict__ f1h, unsigned short* __restrict__ f1l)
{
    int i = blockIdx.x * 256 + threadIdx.x;
    int pos = i >> 17, rem = i & 131071, o = rem >> 8, c = rem & 255;
    float v = fc1w[(size_t)o * 4096 + c * 16 + pos];
    unsigned short h, l; split2(v, &h, &l);
    f1h[i] = h; f1l[i] = l;
}

// ============================ lut: LUT[pos][code][out] ============================
__global__ __launch_bounds__(256, 2) void lut_kernel(
    const unsigned short* __restrict__ codh, const unsigned short* __restrict__ codl,
    const unsigned short* __restrict__ f1h, const unsigned short* __restrict__ f1l,
    float* __restrict__ lut)
{
    const int t = threadIdx.x, b = blockIdx.x;
    const int pos = b >> 5, sub = b & 31, mblk = sub >> 2, nblk = sub & 3;
    const int wv = t >> 6, lane = t & 63, lq = lane >> 4, lm = lane & 15;
    const int mh = wv >> 1, nh = wv & 1;
    f32x4 acc[4][4];
    #pragma unroll
    for (int i = 0; i < 4; ++i)
        #pragma unroll
        for (int j = 0; j < 4; ++j) acc[i][j] = (f32x4){0.f, 0.f, 0.f, 0.f};
    #pragma unroll
    for (int ks = 0; ks < 8; ++ks) {
        bf16x8 ah[4], al[4];
        #pragma unroll
        for (int mt = 0; mt < 4; ++mt) {
            int code = mblk * 128 + mh * 64 + mt * 16 + lm;
            ah[mt] = *(const bf16x8*)(codh + (size_t)code * 256 + ks * 32 + lq * 8);
            al[mt] = *(const bf16x8*)(codl + (size_t)code * 256 + ks * 32 + lq * 8);
        }
        #pragma unroll
        for (int nt = 0; nt < 4; ++nt) {
            int o = nblk * 128 + nh * 64 + nt * 16 + lm;
            bf16x8 bh = *(const bf16x8*)(f1h + ((size_t)pos * 512 + o) * 256 + ks * 32 + lq * 8);
            bf16x8 bl = *(const bf16x8*)(f1l + ((size_t)pos * 512 + o) * 256 + ks * 32 + lq * 8);
            #pragma unroll
            for (int mt = 0; mt < 4; ++mt) {
                acc[mt][nt] = MFMA16(ah[mt], bh, acc[mt][nt]);
                acc[mt][nt] = MFMA16(ah[mt], bl, acc[mt][nt]);
                acc[mt][nt] = MFMA16(al[mt], bh, acc[mt][nt]);
            }
        }
    }
    #pragma unroll
    for (int nt = 0; nt < 4; ++nt) {
        int o = nblk * 128 + nh * 64 + nt * 16 + lm;
        #pragma unroll
        for (int mt = 0; mt < 4; ++mt)
            #pragma unroll
            for (int r = 0; r < 4; ++r) {
                int code = mblk * 128 + mh * 64 + mt * 16 + lq * 4 + r;
                lut[((size_t)pos * 1024 + code) * 512 + o] = acc[mt][nt][r];
            }
    }
}

// ============================ hsum ============================
__device__ inline float gelu_tanh(float x) {
    float x3 = x * x * x;
    float u = 0.7978845608028654f * (x + 0.044715f * x3);
    return 0.5f * x * (1.0f + tanhf(u));
}

__global__ __launch_bounds__(256) void hsum_kernel(
    const int* __restrict__ enc, const float* __restrict__ lut,
    const float* __restrict__ fc1b, float* __restrict__ h)
{
    __shared__ int e[16];
    const int t = threadIdx.x, img = blockIdx.x;
    if (t < 16) e[t] = enc[img * 16 + t];
    __syncthreads();
    for (int rep = 0; rep < 2; ++rep) {
        int o = rep * 256 + t;
        float acc = fc1b[o];
        #pragma unroll
        for (int p = 0; p < 16; ++p)
            acc += lut[((size_t)p * 1024 + e[p]) * 512 + o];
        h[(size_t)img * 512 + o] = gelu_tanh(acc);
    }
}

// ============================ fc2 ============================
__global__ __launch_bounds__(256) void fc2_kernel(
    const float* __restrict__ h, const float* __restrict__ fc2w,
    const float* __restrict__ fc2b, float* __restrict__ out)
{
    __shared__ float ws2[10 * 512];
    const int t = threadIdx.x;
    for (int i = t; i < 5120; i += 256) ws2[i] = fc2w[i];
    __syncthreads();
    const int lane = t & 63, wv = t >> 6;
    const int n = blockIdx.x * 4 + wv;
    float acc[10];
    #pragma unroll
    for (int j = 0; j < 10; ++j) acc[j] = 0.f;
    #pragma unroll
    for (int i = 0; i < 8; ++i) {
        float hv = h[(size_t)n * 512 + lane + 64 * i];
        #pragma unroll
        for (int j = 0; j < 10; ++j) acc[j] += hv * ws2[j * 512 + lane + 64 * i];
    }
    #pragma unroll
    for (int j = 0; j < 10; ++j) {
        float v = acc[j];
        for (int off = 32; off; off >>= 1) v += __shfl_down(v, off);
        if (lane == 0) out[(size_t)n * 10 + j] = v + fc2b[j];
    }
}

// ============================ finalize ============================
__global__ __launch_bounds__(256) void finalize_kernel(
    const int* __restrict__ counts, const float* __restrict__ lsum,
    const int* __restrict__ idxp, float* __restrict__ out)
{
    __shared__ float red[256];
    const int t = threadIdx.x;
    const int Kc = (idxp[0] == 0) ? 512 : 1024;
    float s = 0.f;
    for (int k = t; k < Kc; k += 256) {
        float p = (float)counts[k] * (1.0f / 65536.0f);
        s += p * logf(p + 1e-10f);
    }
    red[t] = s;
    __syncthreads();
    for (int o = 128; o; o >>= 1) {
        if (t < o) red[t] += red[t + o];
        __syncthreads();
    }
    if (t == 0) {
        out[40960] = lsum[0] * (1.25f / 16777216.0f);
        out[40961] = expf(-red[0]);
    }
}

// ============================ launch ============================
extern "C" void kernel_launch(void* const* d_in, const int* in_sizes, int n_in,
                              void* d_out, int out_size, void* d_ws, size_t ws_size,
                              hipStream_t stream)
{
    const float* x     = (const float*)d_in[0];
    const float* w1    = (const float*)d_in[1];
    const float* b1    = (const float*)d_in[2];
    const float* w2    = (const float*)d_in[3];
    const float* b2    = (const float*)d_in[4];
    const float* w3    = (const float*)d_in[5];
    const float* b3    = (const float*)d_in[6];
    const float* code0 = (const float*)d_in[7];
    const float* code1 = (const float*)d_in[8];
    const float* fc1w  = (const float*)d_in[9];
    const float* fc1b  = (const float*)d_in[10];
    const float* fc2w  = (const float*)d_in[11];
    const float* fc2b  = (const float*)d_in[12];
    const int*   idxp  = (const int*)d_in[13];
    float* out = (float*)d_out;
    char* ws = (char*)d_ws;

    unsigned short* w1sh = (unsigned short*)(ws + OFF_W1SH);
    unsigned short* w1sl = (unsigned short*)(ws + OFF_W1SL);
    unsigned short* w2sh = (unsigned short*)(ws + OFF_W2SH);
    unsigned short* w2sl = (unsigned short*)(ws + OFF_W2SL);
    unsigned short* w3sh = (unsigned short*)(ws + OFF_W3SH);
    unsigned short* w3sl = (unsigned short*)(ws + OFF_W3SL);
    unsigned short* codh = (unsigned short*)(ws + OFF_CODH);
    unsigned short* codl = (unsigned short*)(ws + OFF_CODL);
    unsigned short* codT = (unsigned short*)(ws + OFF_CODS);
    float* cnorm = (float*)(ws + OFF_CNORM);
    int*   counts= (int*)(ws + OFF_COUNTS);
    float* lsum  = (float*)(ws + OFF_LOSS);
    int*   enc   = (int*)(ws + OFF_ENC);
    unsigned short* y2h = (unsigned short*)(ws + OFF_BIG);
    unsigned short* y2l = (unsigned short*)(ws + OFF_BIG + 67108864);
    unsigned short* fhS = (unsigned short*)(ws + OFF_FLATS);
    unsigned short* flS = (unsigned short*)(ws + OFF_FLATS + 33554432);
    float* lut = (float*)(ws + OFF_BIG);
    float* h   = (float*)(ws + OFF_BIG + 33554432);
    unsigned short* f1h = (unsigned short*)(ws + OFF_FLATS);
    unsigned short* f1l = (unsigned short*)(ws + OFF_FLATS + 4194304);

    prep1_kernel<<<4529, 256, 0, stream>>>(w1, w2, w3, code0, code1, idxp,
                                           w1sh, w1sl, w2sh, w2sl, w3sh, w3sl,
                                           codh, codl, codT, cnorm, counts, lsum);
    conv12_kernel<<<8192, 256, 0, stream>>>(x, w1sh, w1sl, b1, w2sh, w2sl, b2, y2h, y2l);
    conv3_kernel<<<512, 256, 0, stream>>>(y2h, y2l, w3sh, w3sl, b3, fhS, flS, lsum);
    vq_kernel<<<1024, 256, 0, stream>>>(fhS, flS, codT, cnorm, idxp, enc, counts, lsum);
    prep2_kernel<<<8192, 256, 0, stream>>>(fc1w, f1h, f1l);
    lut_kernel<<<512, 256, 0, stream>>>(codh, codl, f1h, f1l, lut);
    hsum_kernel<<<4096, 256, 0, stream>>>(enc, lut, fc1b, h);
    fc2_kernel<<<1024, 256, 0, stream>>>(h, fc2w, fc2b, out);
    finalize_kernel<<<1, 256, 0, stream>>>(counts, lsum, idxp, out);
}